// Round 1
// baseline (654.755 us; speedup 1.0000x reference)
//
#include <hip/hip_runtime.h>

typedef unsigned short u16;
typedef __attribute__((ext_vector_type(8))) short short8;
typedef __attribute__((ext_vector_type(4))) float float4v;

#define MFMA_BF16(a, b, c) __builtin_amdgcn_mfma_f32_16x16x32_bf16((a), (b), (c), 0, 0, 0)

#define B_ 4
#define S_ 2048
#define D_ 1024
#define H_ 8
#define DH_ 128
#define DFF_ 4096
#define EPS_ 1e-5f
#define ROWS_ (B_ * S_)   // 8192

__device__ __forceinline__ u16 f2bf(float f) {
  union { float f; unsigned u; } x; x.f = f;
  unsigned r = x.u + 0x7fffu + ((x.u >> 16) & 1u);
  return (u16)(r >> 16);
}

// ---------------- cast fp32 -> bf16 (layout preserved) ----------------
__global__ void cast_bf16_kernel(const float* __restrict__ in, u16* __restrict__ out, int n4) {
  int i = blockIdx.x * blockDim.x + threadIdx.x;
  int stride = gridDim.x * blockDim.x;
  for (; i < n4; i += stride) {
    float4 v = ((const float4*)in)[i];
    ushort4 u;
    u.x = f2bf(v.x); u.y = f2bf(v.y); u.z = f2bf(v.z); u.w = f2bf(v.w);
    ((ushort4*)out)[i] = u;
  }
}

// ---------- cast+transpose fp32 [K][N] -> bf16 [N][K] (weights) ----------
__global__ void transpose_cast_kernel(const float* __restrict__ in, u16* __restrict__ out,
                                      int K, int N) {
  __shared__ float t[32][33];
  int k0 = blockIdx.x * 32, n0 = blockIdx.y * 32;
  int tx = threadIdx.x & 31, ty = threadIdx.x >> 5;  // 32x8 threads
  #pragma unroll
  for (int i = 0; i < 4; ++i)
    t[ty + 8 * i][tx] = in[(size_t)(k0 + ty + 8 * i) * N + n0 + tx];
  __syncthreads();
  #pragma unroll
  for (int i = 0; i < 4; ++i)
    out[(size_t)(n0 + ty + 8 * i) * K + k0 + tx] = f2bf(t[tx][ty + 8 * i]);
}

// ------- transpose V bf16 [bh][S][DH] -> [bh][DH][S] (for PV B-operand) -------
__global__ void transpose_v_kernel(const u16* __restrict__ in, u16* __restrict__ out) {
  __shared__ u16 t[32][33];
  int s0 = blockIdx.x * 32, d0 = blockIdx.y * 32, bh = blockIdx.z;
  const u16* src = in + (size_t)bh * S_ * DH_;
  u16* dst = out + (size_t)bh * DH_ * S_;
  int tx = threadIdx.x & 31, ty = threadIdx.x >> 5;
  #pragma unroll
  for (int i = 0; i < 4; ++i)
    t[ty + 8 * i][tx] = src[(size_t)(s0 + ty + 8 * i) * DH_ + d0 + tx];
  __syncthreads();
  #pragma unroll
  for (int i = 0; i < 4; ++i)
    dst[(size_t)(d0 + ty + 8 * i) * S_ + s0 + tx] = t[tx][ty + 8 * i];
}

// ---------------- bf16 MFMA GEMM: C[M,N] = A[M,K] @ Bt[N,K]^T ----------------
// MODE 0: scatter q/k/v bf16 ([b,h,s,dh]); MODE 1: fp32 store;
// MODE 2: +bias, relu, bf16 store;       MODE 3: +bias, fp32 store.
template <int MODE>
__global__ __launch_bounds__(256) void gemm_kernel(
    const u16* __restrict__ A, const u16* __restrict__ Bt,
    const int M, const int N, const int K,
    float* __restrict__ outF, u16* __restrict__ outH, const float* __restrict__ bias,
    u16* __restrict__ qo, u16* __restrict__ ko, u16* __restrict__ vo) {
  __shared__ u16 As[128][40];  // +8 pad: 2-way bank aliasing only (free)
  __shared__ u16 Bs[128][40];
  const int tid = threadIdx.x;
  const int lane = tid & 63, wave = tid >> 6;
  const int quad = lane >> 4, r16 = lane & 15;
  const int wm = (wave >> 1) * 64, wn = (wave & 1) * 64;
  const int m0 = blockIdx.x * 128, n0 = blockIdx.y * 128;

  float4v acc[4][4];
  #pragma unroll
  for (int i = 0; i < 4; ++i)
    #pragma unroll
    for (int j = 0; j < 4; ++j) acc[i][j] = (float4v)0.0f;

  // staging: 512 chunks of 8 bf16; 2 per thread per matrix
  const int srow = tid >> 2, sseg = tid & 3;
  const u16* Ap0 = A + (size_t)(m0 + srow) * K + sseg * 8;
  const u16* Ap1 = A + (size_t)(m0 + srow + 64) * K + sseg * 8;
  const u16* Bp0 = Bt + (size_t)(n0 + srow) * K + sseg * 8;
  const u16* Bp1 = Bt + (size_t)(n0 + srow + 64) * K + sseg * 8;

  for (int k0 = 0; k0 < K; k0 += 32) {
    short8 a0 = *(const short8*)(Ap0 + k0);
    short8 a1 = *(const short8*)(Ap1 + k0);
    short8 b0 = *(const short8*)(Bp0 + k0);
    short8 b1 = *(const short8*)(Bp1 + k0);
    __syncthreads();
    *(short8*)&As[srow][sseg * 8] = a0;
    *(short8*)&As[srow + 64][sseg * 8] = a1;
    *(short8*)&Bs[srow][sseg * 8] = b0;
    *(short8*)&Bs[srow + 64][sseg * 8] = b1;
    __syncthreads();
    short8 af[4], bf[4];
    #pragma unroll
    for (int t = 0; t < 4; ++t) af[t] = *(const short8*)&As[wm + t * 16 + r16][quad * 8];
    #pragma unroll
    for (int t = 0; t < 4; ++t) bf[t] = *(const short8*)&Bs[wn + t * 16 + r16][quad * 8];
    #pragma unroll
    for (int i = 0; i < 4; ++i)
      #pragma unroll
      for (int j = 0; j < 4; ++j) acc[i][j] = MFMA_BF16(af[i], bf[j], acc[i][j]);
  }

  // epilogue: D row = quad*4+reg, col = r16 within each 16x16 tile
  #pragma unroll
  for (int i = 0; i < 4; ++i) {
    const int rowb = m0 + wm + i * 16 + quad * 4;
    #pragma unroll
    for (int j = 0; j < 4; ++j) {
      const int col = n0 + wn + j * 16 + r16;
      #pragma unroll
      for (int rg = 0; rg < 4; ++rg) {
        float val = acc[i][j][rg];
        const int r = rowb + rg;
        if (MODE == 0) {
          const int part = col >> 10, cc = col & 1023;
          const int h = cc >> 7, dh = cc & 127;
          const int b = r >> 11, s = r & 2047;
          u16* dst = (part == 0) ? qo : (part == 1) ? ko : vo;
          dst[((size_t)(b * H_ + h) * S_ + s) * DH_ + dh] = f2bf(val);
        } else if (MODE == 1) {
          outF[(size_t)r * N + col] = val;
        } else if (MODE == 2) {
          val += bias[col];
          val = fmaxf(val, 0.0f);
          outH[(size_t)r * N + col] = f2bf(val);
        } else {
          val += bias[col];
          outF[(size_t)r * N + col] = val;
        }
      }
    }
  }
}

// ---------------- flash causal attention ----------------
// Q,K: [bh][S][DH] bf16; Vt_g: [bh][DH][S] bf16; O: [rows=8192][D] bf16 ([b,s,h*dh])
__global__ __launch_bounds__(256) void attn_kernel(
    const u16* __restrict__ Q, const u16* __restrict__ Kg,
    const u16* __restrict__ Vtg, u16* __restrict__ O) {
  __shared__ u16 Ks[64][136];       // [kc][d], +8 pad
  __shared__ u16 Vt[128][72];       // [d][kc], +8 pad
  __shared__ u16 Pw[4][16][72];     // per-wave P strip [qr][kc]
  const int tid = threadIdx.x;
  const int lane = tid & 63, wave = tid >> 6;
  const int quad = lane >> 4, r16 = lane & 15;
  const int qb = blockIdx.x;   // 32 q-blocks of 64
  const int bh = blockIdx.y;   // 32
  const size_t base = (size_t)bh * S_ * DH_;
  const size_t vtb = (size_t)bh * DH_ * S_;

  // Q strip (16 rows per wave) in A-operand layout: m=r16, k=quad*8+j
  short8 aq[4];
  const int qrow = qb * 64 + wave * 16 + r16;
  #pragma unroll
  for (int ks = 0; ks < 4; ++ks)
    aq[ks] = *(const short8*)(Q + base + (size_t)qrow * DH_ + ks * 32 + quad * 8);

  float4v acco[8];
  #pragma unroll
  for (int i = 0; i < 8; ++i) acco[i] = (float4v)0.0f;
  float mrow[4], lrow[4];
  #pragma unroll
  for (int r = 0; r < 4; ++r) { mrow[r] = -1e30f; lrow[r] = 0.0f; }

  const float scale = 0.08838834764831845f;  // 1/sqrt(128)

  for (int kb = 0; kb <= qb; ++kb) {
    __syncthreads();
    // stage K block [64][128]
    #pragma unroll
    for (int i = 0; i < 4; ++i) {
      int c = tid + i * 256;
      int row = c >> 4, seg = c & 15;
      *(short8*)&Ks[row][seg * 8] =
          *(const short8*)(Kg + base + (size_t)(kb * 64 + row) * DH_ + seg * 8);
    }
    // stage Vt block [128][64] from pre-transposed V (coalesced, conflict-free)
    #pragma unroll
    for (int i = 0; i < 4; ++i) {
      int c = tid + i * 256;
      int d = c >> 3, seg = c & 7;
      *(short8*)&Vt[d][seg * 8] =
          *(const short8*)(Vtg + vtb + (size_t)d * S_ + kb * 64 + seg * 8);
    }
    __syncthreads();

    // S strip = Q Kt : 16 rows x 64 cols per wave
    float4v accs[4];
    #pragma unroll
    for (int t = 0; t < 4; ++t) accs[t] = (float4v)0.0f;
    #pragma unroll
    for (int ks = 0; ks < 4; ++ks) {
      #pragma unroll
      for (int t = 0; t < 4; ++t) {
        short8 bk = *(const short8*)&Ks[t * 16 + r16][ks * 32 + quad * 8];
        accs[t] = MFMA_BF16(aq[ks], bk, accs[t]);
      }
    }
    // scale + causal mask (diagonal block only)
    if (kb == qb) {
      #pragma unroll
      for (int t = 0; t < 4; ++t)
        #pragma unroll
        for (int rg = 0; rg < 4; ++rg) {
          int kc = kb * 64 + t * 16 + r16;
          int qr = qb * 64 + wave * 16 + quad * 4 + rg;
          accs[t][rg] = (kc > qr) ? -1e30f : accs[t][rg] * scale;
        }
    } else {
      #pragma unroll
      for (int t = 0; t < 4; ++t)
        #pragma unroll
        for (int rg = 0; rg < 4; ++rg) accs[t][rg] *= scale;
    }

    // online softmax; row r = quad*4+rg lives on the 16 lanes of this quad
    float alpha[4];
    #pragma unroll
    for (int rg = 0; rg < 4; ++rg) {
      float mv = fmaxf(fmaxf(accs[0][rg], accs[1][rg]), fmaxf(accs[2][rg], accs[3][rg]));
      mv = fmaxf(mv, __shfl_xor(mv, 1));
      mv = fmaxf(mv, __shfl_xor(mv, 2));
      mv = fmaxf(mv, __shfl_xor(mv, 4));
      mv = fmaxf(mv, __shfl_xor(mv, 8));
      float mnew = fmaxf(mrow[rg], mv);
      alpha[rg] = __expf(mrow[rg] - mnew);
      float s0 = 0.0f;
      #pragma unroll
      for (int t = 0; t < 4; ++t) {
        float p = __expf(accs[t][rg] - mnew);
        accs[t][rg] = p;
        s0 += p;
      }
      s0 += __shfl_xor(s0, 1);
      s0 += __shfl_xor(s0, 2);
      s0 += __shfl_xor(s0, 4);
      s0 += __shfl_xor(s0, 8);
      lrow[rg] = lrow[rg] * alpha[rg] + s0;
      mrow[rg] = mnew;
    }
    // rescale O accumulator
    #pragma unroll
    for (int nt = 0; nt < 8; ++nt)
      #pragma unroll
      for (int rg = 0; rg < 4; ++rg) acco[nt][rg] *= alpha[rg];
    // P (C/D layout) -> LDS -> A-operand layout
    #pragma unroll
    for (int t = 0; t < 4; ++t)
      #pragma unroll
      for (int rg = 0; rg < 4; ++rg)
        Pw[wave][quad * 4 + rg][t * 16 + r16] = f2bf(accs[t][rg]);
    asm volatile("s_waitcnt lgkmcnt(0)" ::: "memory");
    // O += P @ V
    #pragma unroll
    for (int ks2 = 0; ks2 < 2; ++ks2) {
      short8 ap = *(const short8*)&Pw[wave][r16][ks2 * 32 + quad * 8];
      #pragma unroll
      for (int nt = 0; nt < 8; ++nt) {
        short8 bv = *(const short8*)&Vt[nt * 16 + r16][ks2 * 32 + quad * 8];
        acco[nt] = MFMA_BF16(ap, bv, acco[nt]);
      }
    }
  }

  // epilogue: O[b*S+s][h*128+d] bf16
  const int b = bh >> 3, h = bh & 7;
  const int sbase = qb * 64 + wave * 16 + quad * 4;
  #pragma unroll
  for (int nt = 0; nt < 8; ++nt)
    #pragma unroll
    for (int rg = 0; rg < 4; ++rg) {
      float val = acco[nt][rg] / lrow[rg];
      O[((size_t)(b * S_ + sbase + rg)) * D_ + h * DH_ + nt * 16 + r16] = f2bf(val);
    }
}

// ---------------- layernorm: y = LN(a + res) * g + be ----------------
__global__ __launch_bounds__(256) void ln_kernel(
    const float* __restrict__ a, const float* __restrict__ res,
    const float* __restrict__ g, const float* __restrict__ be,
    float* __restrict__ xf, u16* __restrict__ xb) {
  __shared__ float red[8];
  const int row = blockIdx.x, tid = threadIdx.x;
  const float4 va = ((const float4*)(a + (size_t)row * D_))[tid];
  const float4 vr = ((const float4*)(res + (size_t)row * D_))[tid];
  float4 v;
  v.x = va.x + vr.x; v.y = va.y + vr.y; v.z = va.z + vr.z; v.w = va.w + vr.w;
  float s = v.x + v.y + v.z + v.w;
  float q = v.x * v.x + v.y * v.y + v.z * v.z + v.w * v.w;
  #pragma unroll
  for (int m = 1; m < 64; m <<= 1) {
    s += __shfl_xor(s, m);
    q += __shfl_xor(q, m);
  }
  const int wave = tid >> 6, lane = tid & 63;
  if (lane == 0) { red[wave] = s; red[4 + wave] = q; }
  __syncthreads();
  s = red[0] + red[1] + red[2] + red[3];
  q = red[4] + red[5] + red[6] + red[7];
  const float mu = s * (1.0f / D_);
  const float var = q * (1.0f / D_) - mu * mu;
  const float inv = rsqrtf(var + EPS_);
  const float4 gg = ((const float4*)g)[tid];
  const float4 bb = ((const float4*)be)[tid];
  float4 y;
  y.x = (v.x - mu) * inv * gg.x + bb.x;
  y.y = (v.y - mu) * inv * gg.y + bb.y;
  y.z = (v.z - mu) * inv * gg.z + bb.z;
  y.w = (v.w - mu) * inv * gg.w + bb.w;
  ((float4*)(xf + (size_t)row * D_))[tid] = y;
  if (xb) {
    ushort4 u;
    u.x = f2bf(y.x); u.y = f2bf(y.y); u.z = f2bf(y.z); u.w = f2bf(y.w);
    ((ushort4*)(xb + (size_t)row * D_))[tid] = u;
  }
}

extern "C" void kernel_launch(void* const* d_in, const int* in_sizes, int n_in,
                              void* d_out, int out_size, void* d_ws, size_t ws_size,
                              hipStream_t stream) {
  const float* src   = (const float*)d_in[0];
  const float* w_qkv = (const float*)d_in[1];
  const float* w_out = (const float*)d_in[2];
  const float* w1    = (const float*)d_in[3];
  const float* b1    = (const float*)d_in[4];
  const float* w2    = (const float*)d_in[5];
  const float* b2    = (const float*)d_in[6];
  const float* g1    = (const float*)d_in[7];
  const float* be1   = (const float*)d_in[8];
  const float* g2    = (const float*)d_in[9];
  const float* be2   = (const float*)d_in[10];
  float* out = (float*)d_out;

  char* ws = (char*)d_ws;
  size_t off = 0;
  auto alloc = [&](size_t bytes) -> void* {
    void* p = ws + off;
    off += (bytes + 255) & ~(size_t)255;
    return p;
  };
  u16* src_bf = (u16*)alloc((size_t)ROWS_ * D_ * 2);        // 16.78 MB
  u16* wqkvT  = (u16*)alloc((size_t)3 * D_ * D_ * 2);       //  6.29 MB  [3072][1024]
  u16* woutT  = (u16*)alloc((size_t)D_ * D_ * 2);           //  2.10 MB
  u16* w1T    = (u16*)alloc((size_t)DFF_ * D_ * 2);         //  8.39 MB  [4096][1024]
  u16* w2T    = (u16*)alloc((size_t)D_ * DFF_ * 2);         //  8.39 MB  [1024][4096]
  u16* qbuf   = (u16*)alloc((size_t)ROWS_ * D_ * 2);        // 16.78 MB (4 contiguous)
  u16* kbuf   = (u16*)alloc((size_t)ROWS_ * D_ * 2);
  u16* vbuf   = (u16*)alloc((size_t)ROWS_ * D_ * 2);
  u16* obuf   = (u16*)alloc((size_t)ROWS_ * D_ * 2);
  u16* vT     = (u16*)alloc((size_t)ROWS_ * D_ * 2);        // 16.78 MB
  float* proj = (float*)alloc((size_t)ROWS_ * D_ * 4);      // 33.55 MB
  float* xf   = (float*)alloc((size_t)ROWS_ * D_ * 4);      // 33.55 MB
  u16* xb     = (u16*)alloc((size_t)ROWS_ * D_ * 2);        // 16.78 MB
  u16* h1     = qbuf;   // alias: q,k,v,o dead before GEMM3 writes (exactly 67.1 MB)
  float* ff   = proj;   // alias: proj dead after LN1

  // prologue: cast src, cast+transpose weights
  cast_bf16_kernel<<<2048, 256, 0, stream>>>(src, src_bf, ROWS_ * D_ / 4);
  transpose_cast_kernel<<<dim3(D_ / 32, 3 * D_ / 32), 256, 0, stream>>>(w_qkv, wqkvT, D_, 3 * D_);
  transpose_cast_kernel<<<dim3(D_ / 32, D_ / 32), 256, 0, stream>>>(w_out, woutT, D_, D_);
  transpose_cast_kernel<<<dim3(D_ / 32, DFF_ / 32), 256, 0, stream>>>(w1, w1T, D_, DFF_);
  transpose_cast_kernel<<<dim3(DFF_ / 32, D_ / 32), 256, 0, stream>>>(w2, w2T, DFF_, D_);

  // qkv = src @ w_qkv  -> q,k,v [b,h,s,dh]
  gemm_kernel<0><<<dim3(ROWS_ / 128, 3 * D_ / 128), 256, 0, stream>>>(
      src_bf, wqkvT, ROWS_, 3 * D_, D_, nullptr, nullptr, nullptr, qbuf, kbuf, vbuf);
  // V -> [b,h,dh,s]
  transpose_v_kernel<<<dim3(S_ / 32, DH_ / 32, B_ * H_), 256, 0, stream>>>(vbuf, vT);
  // causal flash attention -> obuf [b,s,h*dh]
  attn_kernel<<<dim3(S_ / 64, B_ * H_), 256, 0, stream>>>(qbuf, kbuf, vT, obuf);
  // proj = o @ w_out (fp32)
  gemm_kernel<1><<<dim3(ROWS_ / 128, D_ / 128), 256, 0, stream>>>(
      obuf, woutT, ROWS_, D_, D_, proj, nullptr, nullptr, nullptr, nullptr, nullptr);
  // x = LN(src + proj)
  ln_kernel<<<ROWS_, 256, 0, stream>>>(proj, src, g1, be1, xf, xb);
  // h1 = relu(x @ w1 + b1) (bf16)
  gemm_kernel<2><<<dim3(ROWS_ / 128, DFF_ / 128), 256, 0, stream>>>(
      xb, w1T, ROWS_, DFF_, D_, nullptr, h1, b1, nullptr, nullptr, nullptr);
  // ff = h1 @ w2 + b2 (fp32)
  gemm_kernel<3><<<dim3(ROWS_ / 128, D_ / 128), 256, 0, stream>>>(
      h1, w2T, ROWS_, D_, DFF_, ff, nullptr, b2, nullptr, nullptr, nullptr);
  // out = LN(x + ff)
  ln_kernel<<<ROWS_, 256, 0, stream>>>(ff, xf, g2, be2, out, nullptr);
}

// Round 2
// 550.001 us; speedup vs baseline: 1.1905x; 1.1905x over previous
//
#include <hip/hip_runtime.h>

typedef unsigned short u16;
typedef __attribute__((ext_vector_type(8))) short short8;
typedef __attribute__((ext_vector_type(4))) float float4v;

#define MFMA_BF16(a, b, c) __builtin_amdgcn_mfma_f32_16x16x32_bf16((a), (b), (c), 0, 0, 0)

#define B_ 4
#define S_ 2048
#define D_ 1024
#define H_ 8
#define DH_ 128
#define DFF_ 4096
#define EPS_ 1e-5f
#define ROWS_ (B_ * S_)   // 8192
#define CSCALE_ 0.12751672939502f  // (1/sqrt(128)) * log2(e), folded into Q

__device__ __forceinline__ u16 f2bf(float f) {
  union { float f; unsigned u; } x; x.f = f;
  unsigned r = x.u + 0x7fffu + ((x.u >> 16) & 1u);
  return (u16)(r >> 16);
}

typedef __attribute__((address_space(1))) const unsigned int guint;
typedef __attribute__((address_space(3))) unsigned int luint;
__device__ __forceinline__ void gl2lds16(const u16* g, u16* l) {
  // each lane: 16B from its own g -> wave-uniform lds base + lane*16
  __builtin_amdgcn_global_load_lds((guint*)g, (luint*)l, 16, 0, 0);
}

// ---------------- cast fp32 -> bf16 (layout preserved) ----------------
__global__ void cast_bf16_kernel(const float* __restrict__ in, u16* __restrict__ out, int n4) {
  int i = blockIdx.x * blockDim.x + threadIdx.x;
  int stride = gridDim.x * blockDim.x;
  for (; i < n4; i += stride) {
    float4 v = ((const float4*)in)[i];
    ushort4 u;
    u.x = f2bf(v.x); u.y = f2bf(v.y); u.z = f2bf(v.z); u.w = f2bf(v.w);
    ((ushort4*)out)[i] = u;
  }
}

// ---------- cast+transpose fp32 [K][N] -> bf16 [N][K] (weights) ----------
__global__ void transpose_cast_kernel(const float* __restrict__ in, u16* __restrict__ out,
                                      int K, int N) {
  __shared__ float t[32][33];
  int k0 = blockIdx.x * 32, n0 = blockIdx.y * 32;
  int tx = threadIdx.x & 31, ty = threadIdx.x >> 5;  // 32x8 threads
  #pragma unroll
  for (int i = 0; i < 4; ++i)
    t[ty + 8 * i][tx] = in[(size_t)(k0 + ty + 8 * i) * N + n0 + tx];
  __syncthreads();
  #pragma unroll
  for (int i = 0; i < 4; ++i)
    out[(size_t)(n0 + ty + 8 * i) * K + k0 + tx] = f2bf(t[tx][ty + 8 * i]);
}

// ------- transpose V bf16 [bh][S][DH] -> [bh][DH][S] (for PV B-operand) -------
__global__ void transpose_v_kernel(const u16* __restrict__ in, u16* __restrict__ out) {
  __shared__ u16 t[32][33];
  int s0 = blockIdx.x * 32, d0 = blockIdx.y * 32, bh = blockIdx.z;
  const u16* src = in + (size_t)bh * S_ * DH_;
  u16* dst = out + (size_t)bh * DH_ * S_;
  int tx = threadIdx.x & 31, ty = threadIdx.x >> 5;
  #pragma unroll
  for (int i = 0; i < 4; ++i)
    t[ty + 8 * i][tx] = src[(size_t)(s0 + ty + 8 * i) * DH_ + d0 + tx];
  __syncthreads();
  #pragma unroll
  for (int i = 0; i < 4; ++i)
    dst[(size_t)(d0 + ty + 8 * i) * S_ + s0 + tx] = t[tx][ty + 8 * i];
}

// ---------------- bf16 MFMA GEMM: C[M,N] = A[M,K] @ Bt[N,K]^T ----------------
// m97 structure: global_load_lds width=16 staging, unpadded [128][32] LDS.
// MODE 0: scatter q/k/v bf16 ([b,h,s,dh], q pre-scaled by CSCALE_);
// MODE 1: fp32 store; MODE 2: +bias, relu, bf16; MODE 3: +bias, fp32.
template <int MODE>
__global__ __launch_bounds__(256) void gemm_kernel(
    const u16* __restrict__ A, const u16* __restrict__ Bt,
    const int M, const int N, const int K,
    float* __restrict__ outF, u16* __restrict__ outH, const float* __restrict__ bias,
    u16* __restrict__ qo, u16* __restrict__ ko, u16* __restrict__ vo) {
  __shared__ u16 As[128][32];  // NO pad: global_load_lds needs lane-contiguous dest
  __shared__ u16 Bs[128][32];
  const int tid = threadIdx.x;
  const int lane = tid & 63, wave = tid >> 6;
  const int quad = lane >> 4, r16 = lane & 15;
  const int wm = (wave >> 1) * 64, wn = (wave & 1) * 64;
  const int m0 = blockIdx.x * 128, n0 = blockIdx.y * 128;

  float4v acc[4][4];
  #pragma unroll
  for (int i = 0; i < 4; ++i)
    #pragma unroll
    for (int j = 0; j < 4; ++j) acc[i][j] = (float4v)0.0f;

  // staging: wave w covers rows [32w, 32w+32) of both tiles, as 2 chunks of
  // 16 rows; within a chunk lane i -> row i/4, 16B segment i%4.
  const int srow = lane >> 2, sseg = lane & 3;
  const u16* Ag0 = A + (size_t)(m0 + wave * 32 + srow) * K + sseg * 8;
  const u16* Ag1 = Ag0 + (size_t)16 * K;
  const u16* Bg0 = Bt + (size_t)(n0 + wave * 32 + srow) * K + sseg * 8;
  const u16* Bg1 = Bg0 + (size_t)16 * K;
  u16* Al0 = &As[wave * 32][0];
  u16* Al1 = &As[wave * 32 + 16][0];
  u16* Bl0 = &Bs[wave * 32][0];
  u16* Bl1 = &Bs[wave * 32 + 16][0];

  for (int k0 = 0; k0 < K; k0 += 32) {
    __syncthreads();           // prior MFMA frag reads done before overwrite
    gl2lds16(Ag0 + k0, Al0);
    gl2lds16(Ag1 + k0, Al1);
    gl2lds16(Bg0 + k0, Bl0);
    gl2lds16(Bg1 + k0, Bl1);
    __syncthreads();           // drains vmcnt -> staged data visible
    short8 af[4], bf[4];
    #pragma unroll
    for (int t = 0; t < 4; ++t) af[t] = *(const short8*)&As[wm + t * 16 + r16][quad * 8];
    #pragma unroll
    for (int t = 0; t < 4; ++t) bf[t] = *(const short8*)&Bs[wn + t * 16 + r16][quad * 8];
    #pragma unroll
    for (int i = 0; i < 4; ++i)
      #pragma unroll
      for (int j = 0; j < 4; ++j) acc[i][j] = MFMA_BF16(af[i], bf[j], acc[i][j]);
  }

  // epilogue: D row = quad*4+reg, col = r16 within each 16x16 tile
  #pragma unroll
  for (int i = 0; i < 4; ++i) {
    const int rowb = m0 + wm + i * 16 + quad * 4;
    #pragma unroll
    for (int j = 0; j < 4; ++j) {
      const int col = n0 + wn + j * 16 + r16;
      #pragma unroll
      for (int rg = 0; rg < 4; ++rg) {
        float val = acc[i][j][rg];
        const int r = rowb + rg;
        if (MODE == 0) {
          const int part = col >> 10, cc = col & 1023;
          const int h = cc >> 7, dh = cc & 127;
          const int b = r >> 11, s = r & 2047;
          u16* dst = (part == 0) ? qo : (part == 1) ? ko : vo;
          if (part == 0) val *= CSCALE_;  // fold softmax scale*log2e into Q
          dst[((size_t)(b * H_ + h) * S_ + s) * DH_ + dh] = f2bf(val);
        } else if (MODE == 1) {
          outF[(size_t)r * N + col] = val;
        } else if (MODE == 2) {
          val += bias[col];
          val = fmaxf(val, 0.0f);
          outH[(size_t)r * N + col] = f2bf(val);
        } else {
          val += bias[col];
          outF[(size_t)r * N + col] = val;
        }
      }
    }
  }
}

// ---------------- flash causal attention (S^T formulation) ----------------
// Q (pre-scaled), K: [bh][S][DH] bf16; Vt: [bh][DH][S] bf16;
// O: [rows][D] bf16. Block = 4 waves, 64 q-rows per tile; each block runs
// q-tiles {p, 31-p} sequentially -> all blocks do exactly 33 kb-iters.
__global__ __launch_bounds__(256) void attn_kernel(
    const u16* __restrict__ Q, const u16* __restrict__ Kg,
    const u16* __restrict__ Vtg, u16* __restrict__ O) {
  __shared__ u16 Ks[64][136];     // [key][d]
  __shared__ u16 Vt[128][72];     // [d][key]
  __shared__ u16 Pw[4][16][72];   // per-wave P [q][key]
  const int tid = threadIdx.x;
  const int lane = tid & 63, wave = tid >> 6;
  const int quad = lane >> 4, r16 = lane & 15;
  const int pairIdx = blockIdx.x;  // 0..15
  const int bh = blockIdx.y;       // 0..31
  const size_t base = (size_t)bh * S_ * DH_;
  const size_t vtb = (size_t)bh * DH_ * S_;
  const int b = bh >> 3, h = bh & 7;

  // hoisted staging addresses
  const u16* kg0 = Kg + base + (size_t)(tid >> 4) * DH_ + (tid & 15) * 8;
  u16* ksl = &Ks[tid >> 4][(tid & 15) * 8];
  const u16* vg0 = Vtg + vtb + (size_t)(tid >> 3) * S_ + (tid & 7) * 8;
  u16* vtl = &Vt[tid >> 3][(tid & 7) * 8];

  for (int half = 0; half < 2; ++half) {
    const int qb = (half == 0) ? pairIdx : 31 - pairIdx;
    const int qr = qb * 64 + wave * 16 + r16;  // this lane's q-row (as B-col)

    // Q fragment: B-operand layout B[k=quad*8+j][n=r16] == Q[q=r16][k] regs
    short8 aq[4];
    #pragma unroll
    for (int ks = 0; ks < 4; ++ks)
      aq[ks] = *(const short8*)(Q + base + (size_t)qr * DH_ + ks * 32 + quad * 8);

    float4v acco[8];
    #pragma unroll
    for (int i = 0; i < 8; ++i) acco[i] = (float4v)0.0f;
    float m_q = -1e30f, l_q = 0.0f;  // per q=r16, replicated across quads

    for (int kb = 0; kb <= qb; ++kb) {
      __syncthreads();
      // stage K block [64][128] and Vt block [128][64]
      #pragma unroll
      for (int i = 0; i < 4; ++i)
        *(short8*)(ksl + i * 16 * 136) =
            *(const short8*)(kg0 + (size_t)(kb * 64 + i * 16) * DH_);
      #pragma unroll
      for (int i = 0; i < 4; ++i)
        *(short8*)(vtl + i * 32 * 72) =
            *(const short8*)(vg0 + (size_t)i * 32 * S_ + kb * 64);
      __syncthreads();

      // S^T tile: rows = keys (64), cols = q (16/wave). A = K, B = Qfrag.
      float4v accs[4];
      #pragma unroll
      for (int t = 0; t < 4; ++t) accs[t] = (float4v)0.0f;
      #pragma unroll
      for (int ks = 0; ks < 4; ++ks) {
        #pragma unroll
        for (int t = 0; t < 4; ++t) {
          short8 ak = *(const short8*)&Ks[t * 16 + r16][ks * 32 + quad * 8];
          accs[t] = MFMA_BF16(ak, aq[ks], accs[t]);
        }
      }
      // causal mask on diagonal block; scores already in log2 domain
      if (kb == qb) {
        #pragma unroll
        for (int t = 0; t < 4; ++t)
          #pragma unroll
          for (int rg = 0; rg < 4; ++rg) {
            int kc = kb * 64 + t * 16 + quad * 4 + rg;
            if (kc > qr) accs[t][rg] = -1e30f;
          }
      }
      // online softmax: lane owns q=r16; 16 local scores + 2 shfl (quads)
      float mv = accs[0][0];
      #pragma unroll
      for (int t = 0; t < 4; ++t)
        #pragma unroll
        for (int rg = 0; rg < 4; ++rg) mv = fmaxf(mv, accs[t][rg]);
      mv = fmaxf(mv, __shfl_xor(mv, 16));
      mv = fmaxf(mv, __shfl_xor(mv, 32));
      const float mnew = fmaxf(m_q, mv);
      const float alpha = __builtin_amdgcn_exp2f(m_q - mnew);
      float s0 = 0.0f;
      #pragma unroll
      for (int t = 0; t < 4; ++t)
        #pragma unroll
        for (int rg = 0; rg < 4; ++rg) {
          float p = __builtin_amdgcn_exp2f(accs[t][rg] - mnew);
          accs[t][rg] = p;
          s0 += p;
        }
      s0 += __shfl_xor(s0, 16);
      s0 += __shfl_xor(s0, 32);
      l_q = l_q * alpha + s0;
      m_q = mnew;

      // P^T (C-layout: 4 consecutive keys/lane) -> Pw[q][key], packed b64
      #pragma unroll
      for (int t = 0; t < 4; ++t) {
        union { float f; unsigned u; } c0, c1, c2, c3;
        c0.f = accs[t][0]; c1.f = accs[t][1]; c2.f = accs[t][2]; c3.f = accs[t][3];
        uint2 pk;
        pk.x = ((c0.u + 0x8000u) >> 16) | ((c1.u + 0x8000u) & 0xffff0000u);
        pk.y = ((c2.u + 0x8000u) >> 16) | ((c3.u + 0x8000u) & 0xffff0000u);
        *(uint2*)&Pw[wave][r16][t * 16 + quad * 4] = pk;
      }
      // rescale O by alpha of its rows q = quad*4+rg
      float al[4];
      #pragma unroll
      for (int rg = 0; rg < 4; ++rg) al[rg] = __shfl(alpha, quad * 4 + rg);
      #pragma unroll
      for (int nt = 0; nt < 8; ++nt)
        #pragma unroll
        for (int rg = 0; rg < 4; ++rg) acco[nt][rg] *= al[rg];
      asm volatile("s_waitcnt lgkmcnt(0)" ::: "memory");
      // O += P @ V
      #pragma unroll
      for (int ks2 = 0; ks2 < 2; ++ks2) {
        short8 ap = *(const short8*)&Pw[wave][r16][ks2 * 32 + quad * 8];
        #pragma unroll
        for (int nt = 0; nt < 8; ++nt) {
          short8 bv = *(const short8*)&Vt[nt * 16 + r16][ks2 * 32 + quad * 8];
          acco[nt] = MFMA_BF16(ap, bv, acco[nt]);
        }
      }
    }

    // epilogue: O rows q=quad*4+rg, cols d=nt*16+r16
    float lr[4];
    #pragma unroll
    for (int rg = 0; rg < 4; ++rg) lr[rg] = __shfl(l_q, quad * 4 + rg);
    const int sbase = qb * 64 + wave * 16 + quad * 4;
    #pragma unroll
    for (int nt = 0; nt < 8; ++nt)
      #pragma unroll
      for (int rg = 0; rg < 4; ++rg) {
        float val = acco[nt][rg] / lr[rg];
        O[((size_t)(b * S_ + sbase + rg)) * D_ + h * DH_ + nt * 16 + r16] = f2bf(val);
      }
  }
}

// ---------------- layernorm: y = LN(a + res) * g + be ----------------
__global__ __launch_bounds__(256) void ln_kernel(
    const float* __restrict__ a, const float* __restrict__ res,
    const float* __restrict__ g, const float* __restrict__ be,
    float* __restrict__ xf, u16* __restrict__ xb) {
  __shared__ float red[8];
  const int row = blockIdx.x, tid = threadIdx.x;
  const float4 va = ((const float4*)(a + (size_t)row * D_))[tid];
  const float4 vr = ((const float4*)(res + (size_t)row * D_))[tid];
  float4 v;
  v.x = va.x + vr.x; v.y = va.y + vr.y; v.z = va.z + vr.z; v.w = va.w + vr.w;
  float s = v.x + v.y + v.z + v.w;
  float q = v.x * v.x + v.y * v.y + v.z * v.z + v.w * v.w;
  #pragma unroll
  for (int m = 1; m < 64; m <<= 1) {
    s += __shfl_xor(s, m);
    q += __shfl_xor(q, m);
  }
  const int wave = tid >> 6, lane = tid & 63;
  if (lane == 0) { red[wave] = s; red[4 + wave] = q; }
  __syncthreads();
  s = red[0] + red[1] + red[2] + red[3];
  q = red[4] + red[5] + red[6] + red[7];
  const float mu = s * (1.0f / D_);
  const float var = q * (1.0f / D_) - mu * mu;
  const float inv = rsqrtf(var + EPS_);
  const float4 gg = ((const float4*)g)[tid];
  const float4 bb = ((const float4*)be)[tid];
  float4 y;
  y.x = (v.x - mu) * inv * gg.x + bb.x;
  y.y = (v.y - mu) * inv * gg.y + bb.y;
  y.z = (v.z - mu) * inv * gg.z + bb.z;
  y.w = (v.w - mu) * inv * gg.w + bb.w;
  ((float4*)(xf + (size_t)row * D_))[tid] = y;
  if (xb) {
    ushort4 u;
    u.x = f2bf(y.x); u.y = f2bf(y.y); u.z = f2bf(y.z); u.w = f2bf(y.w);
    ((ushort4*)(xb + (size_t)row * D_))[tid] = u;
  }
}

extern "C" void kernel_launch(void* const* d_in, const int* in_sizes, int n_in,
                              void* d_out, int out_size, void* d_ws, size_t ws_size,
                              hipStream_t stream) {
  const float* src   = (const float*)d_in[0];
  const float* w_qkv = (const float*)d_in[1];
  const float* w_out = (const float*)d_in[2];
  const float* w1    = (const float*)d_in[3];
  const float* b1    = (const float*)d_in[4];
  const float* w2    = (const float*)d_in[5];
  const float* b2    = (const float*)d_in[6];
  const float* g1    = (const float*)d_in[7];
  const float* be1   = (const float*)d_in[8];
  const float* g2    = (const float*)d_in[9];
  const float* be2   = (const float*)d_in[10];
  float* out = (float*)d_out;

  char* ws = (char*)d_ws;
  size_t off = 0;
  auto alloc = [&](size_t bytes) -> void* {
    void* p = ws + off;
    off += (bytes + 255) & ~(size_t)255;
    return p;
  };
  u16* src_bf = (u16*)alloc((size_t)ROWS_ * D_ * 2);
  u16* wqkvT  = (u16*)alloc((size_t)3 * D_ * D_ * 2);   // [3072][1024]
  u16* woutT  = (u16*)alloc((size_t)D_ * D_ * 2);
  u16* w1T    = (u16*)alloc((size_t)DFF_ * D_ * 2);     // [4096][1024]
  u16* w2T    = (u16*)alloc((size_t)D_ * DFF_ * 2);     // [1024][4096]
  u16* qbuf   = (u16*)alloc((size_t)ROWS_ * D_ * 2);
  u16* kbuf   = (u16*)alloc((size_t)ROWS_ * D_ * 2);
  u16* vbuf   = (u16*)alloc((size_t)ROWS_ * D_ * 2);
  u16* obuf   = (u16*)alloc((size_t)ROWS_ * D_ * 2);
  u16* vT     = (u16*)alloc((size_t)ROWS_ * D_ * 2);
  float* proj = (float*)alloc((size_t)ROWS_ * D_ * 4);
  float* xf   = (float*)alloc((size_t)ROWS_ * D_ * 4);
  u16* xb     = (u16*)alloc((size_t)ROWS_ * D_ * 2);
  u16* h1     = qbuf;   // alias: q,k,v,o dead before GEMM3 writes
  float* ff   = proj;   // alias: proj dead after LN1

  cast_bf16_kernel<<<2048, 256, 0, stream>>>(src, src_bf, ROWS_ * D_ / 4);
  transpose_cast_kernel<<<dim3(D_ / 32, 3 * D_ / 32), 256, 0, stream>>>(w_qkv, wqkvT, D_, 3 * D_);
  transpose_cast_kernel<<<dim3(D_ / 32, D_ / 32), 256, 0, stream>>>(w_out, woutT, D_, D_);
  transpose_cast_kernel<<<dim3(D_ / 32, DFF_ / 32), 256, 0, stream>>>(w1, w1T, D_, DFF_);
  transpose_cast_kernel<<<dim3(DFF_ / 32, D_ / 32), 256, 0, stream>>>(w2, w2T, DFF_, D_);

  gemm_kernel<0><<<dim3(ROWS_ / 128, 3 * D_ / 128), 256, 0, stream>>>(
      src_bf, wqkvT, ROWS_, 3 * D_, D_, nullptr, nullptr, nullptr, qbuf, kbuf, vbuf);
  transpose_v_kernel<<<dim3(S_ / 32, DH_ / 32, B_ * H_), 256, 0, stream>>>(vbuf, vT);
  attn_kernel<<<dim3(16, B_ * H_), 256, 0, stream>>>(qbuf, kbuf, vT, obuf);
  gemm_kernel<1><<<dim3(ROWS_ / 128, D_ / 128), 256, 0, stream>>>(
      obuf, woutT, ROWS_, D_, D_, proj, nullptr, nullptr, nullptr, nullptr, nullptr);
  ln_kernel<<<ROWS_, 256, 0, stream>>>(proj, src, g1, be1, xf, xb);
  gemm_kernel<2><<<dim3(ROWS_ / 128, DFF_ / 128), 256, 0, stream>>>(
      xb, w1T, ROWS_, DFF_, D_, nullptr, h1, b1, nullptr, nullptr, nullptr);
  gemm_kernel<3><<<dim3(ROWS_ / 128, D_ / 128), 256, 0, stream>>>(
      h1, w2T, ROWS_, D_, DFF_, ff, nullptr, b2, nullptr, nullptr, nullptr);
  ln_kernel<<<ROWS_, 256, 0, stream>>>(ff, xf, g2, be2, out, nullptr);
}